// Round 1
// baseline (332.148 us; speedup 1.0000x reference)
//
#include <hip/hip_runtime.h>

#define Bn 4
#define Nn 512
#define Tn 10
#define Fn 516      // N + 4
#define MH 128      // MSG_HID
#define MD 32       // MSG_DIM
#define UH 128      // UPD_HID
#define OD 4        // OUT_DIM

#define JS 64               // j-splits
#define JPB (Nn / JS)       // j's per block = 8

// ---------------- Kernel A: Abase[b*N+j][128] = mb1 + sum_{t,c<4} x[b,j,t,c]*mW1[5t+c][:]
__global__ __launch_bounds__(128) void kA(const float* __restrict__ x,
                                          const float* __restrict__ mW1,
                                          const float* __restrict__ mb1,
                                          float* __restrict__ Abase) {
  int bj = blockIdx.x;          // 0..B*N-1
  int k  = threadIdx.x;         // 0..127
  const float* xr = x + (size_t)bj * Tn * Fn;
  float acc = mb1[k];
#pragma unroll
  for (int t = 0; t < Tn; ++t) {
#pragma unroll
    for (int c = 0; c < 4; ++c) {
      acc = fmaf(xr[t * Fn + c], mW1[(t * 5 + c) * MH + k], acc);
    }
  }
  Abase[(size_t)bj * MH + k] = acc;
}

// ---------------- Kernel B: per pair (i,j) message MLP, accumulate msg_sum over j
__global__ __launch_bounds__(256) void kB(const float* __restrict__ x,
                                          const float* __restrict__ Abase,
                                          const float* __restrict__ mW1,
                                          const float* __restrict__ mW2,
                                          float* __restrict__ msum) {
  int bx    = blockIdx.x;          // B * 2 * JS blocks
  int jblk  = bx & (JS - 1);
  int itile = (bx >> 6) & 1;
  int b     = bx >> 7;
  int i     = itile * 256 + threadIdx.x;

  float m[MD];
#pragma unroll
  for (int c = 0; c < MD; ++c) m[c] = 0.f;

#pragma unroll 1
  for (int jj = 0; jj < JPB; ++jj) {
    int j = jblk * JPB + jj;
    const float* xe = x + ((size_t)(b * Nn + j) * Tn) * Fn + 4 + i;
    float e[Tn];
#pragma unroll
    for (int t = 0; t < Tn; ++t) e[t] = xe[t * Fn];   // coalesced over i

    const float* Ar = Abase + (size_t)(b * Nn + j) * MH;

#pragma unroll 1
    for (int kc = 0; kc < MH / 16; ++kc) {
      float p[16];
#pragma unroll
      for (int k = 0; k < 16; ++k) {
        float a = Ar[kc * 16 + k];                    // uniform -> s_load
#pragma unroll
        for (int t = 0; t < Tn; ++t) {
          a = fmaf(e[t], mW1[(t * 5 + 4) * MH + kc * 16 + k], a);  // uniform weight
        }
        p[k] = fmaxf(a, 0.f);
      }
#pragma unroll
      for (int k = 0; k < 16; ++k) {
#pragma unroll
        for (int c = 0; c < MD; ++c) {
          m[c] = fmaf(p[k], mW2[(kc * 16 + k) * MD + c], m[c]);    // uniform weight
        }
      }
    }
  }

  float* dst = msum + ((size_t)(b * Nn) + i) * MD;
#pragma unroll
  for (int c = 0; c < MD; ++c) atomicAdd(dst + c, m[c]);
}

// ---------------- Kernel C: per (b,i) final MLP 36 -> 128 -> 4
__global__ __launch_bounds__(128) void kC(const float* __restrict__ x,
                                          const float* __restrict__ msum,
                                          const float* __restrict__ mb2,
                                          const float* __restrict__ iW1,
                                          const float* __restrict__ ib1,
                                          const float* __restrict__ iW2,
                                          const float* __restrict__ ib2,
                                          float* __restrict__ out) {
  int bi = blockIdx.x;          // 0..B*N-1
  int k  = threadIdx.x;         // 0..127
  __shared__ float red[UH][OD];

  const float* ms = msum + (size_t)bi * MD;
  const float* nf = x + ((size_t)bi * Tn + (Tn - 1)) * Fn;  // x[b,i,T-1,0:4]

  float a = ib1[k];
#pragma unroll
  for (int c = 0; c < MD; ++c) {
    // msg had +mb2 per message; summed over N messages
    a = fmaf(ms[c] + (float)Nn * mb2[c], iW1[c * UH + k], a);
  }
#pragma unroll
  for (int c = 0; c < 4; ++c) {
    a = fmaf(nf[c], iW1[(MD + c) * UH + k], a);
  }
  a = fmaxf(a, 0.f);
#pragma unroll
  for (int c = 0; c < OD; ++c) red[k][c] = a * iW2[k * OD + c];
  __syncthreads();

  if (k < OD) {
    float s = ib2[k];
    for (int kk = 0; kk < UH; ++kk) s += red[kk][k];
    out[(size_t)bi * OD + k] = s;
  }
}

extern "C" void kernel_launch(void* const* d_in, const int* in_sizes, int n_in,
                              void* d_out, int out_size, void* d_ws, size_t ws_size,
                              hipStream_t stream) {
  const float* x   = (const float*)d_in[0];
  const float* mW1 = (const float*)d_in[1];
  const float* mb1 = (const float*)d_in[2];
  const float* mW2 = (const float*)d_in[3];
  const float* mb2 = (const float*)d_in[4];
  const float* iW1 = (const float*)d_in[5];
  const float* ib1 = (const float*)d_in[6];
  const float* iW2 = (const float*)d_in[7];
  const float* ib2 = (const float*)d_in[8];
  float* out = (float*)d_out;

  float* Abase = (float*)d_ws;                         // B*N*128 floats
  float* msum  = Abase + (size_t)Bn * Nn * MH;         // B*N*32 floats

  hipMemsetAsync(msum, 0, (size_t)Bn * Nn * MD * sizeof(float), stream);

  kA<<<Bn * Nn, 128, 0, stream>>>(x, mW1, mb1, Abase);
  kB<<<Bn * 2 * JS, 256, 0, stream>>>(x, Abase, mW1, mW2, msum);
  kC<<<Bn * Nn, 128, 0, stream>>>(x, msum, mb2, iW1, ib1, iW2, ib2, out);
}

// Round 2
// 126.769 us; speedup vs baseline: 2.6201x; 2.6201x over previous
//
#include <hip/hip_runtime.h>
#include <hip/hip_bf16.h>

#define Bn 4
#define Nn 512
#define Tn 10
#define Fn 516      // N + 4
#define MH 128      // MSG_HID
#define MD 32       // MSG_DIM
#define UH 128      // UPD_HID
#define OD 4        // OUT_DIM

#define JSPLIT 64
#define JPB (Nn / JSPLIT)   // 8 j's per block

typedef __attribute__((ext_vector_type(8))) short short8;   // 8 bf16 = 4 VGPRs
typedef __attribute__((ext_vector_type(4))) float floatx4;

static __device__ inline unsigned pk2(float a, float b) {
  union { __hip_bfloat162 h; unsigned u; } cv;
  cv.h = __float22bfloat162_rn(make_float2(a, b));
  return cv.u;
}

static __device__ inline short8 pack8(const float* v) {
  union { short8 s; unsigned u[4]; } cv;
#pragma unroll
  for (int r = 0; r < 4; ++r) cv.u[r] = pk2(v[2 * r], v[2 * r + 1]);
  return cv.s;
}

// ---------------- Kernel A: Abase[b*N+j][128] = mb1 + sum_{t,c<4} x[b,j,t,c]*mW1[5t+c][:]
__global__ __launch_bounds__(128) void kA(const float* __restrict__ x,
                                          const float* __restrict__ mW1,
                                          const float* __restrict__ mb1,
                                          float* __restrict__ Abase) {
  int bj = blockIdx.x;
  int k  = threadIdx.x;
  const float* xr = x + (size_t)bj * Tn * Fn;
  float acc = mb1[k];
#pragma unroll
  for (int t = 0; t < Tn; ++t)
#pragma unroll
    for (int c = 0; c < 4; ++c)
      acc = fmaf(xr[t * Fn + c], mW1[(t * 5 + c) * MH + k], acc);
  Abase[(size_t)bj * MH + k] = acc;
}

// ---------------- Kernel B (MFMA): per (b,j): P = relu(W1e^T . E^T + Abase); msum += P . W2
__global__ __launch_bounds__(256) void kB(const float* __restrict__ x,
                                          const float* __restrict__ Abase,
                                          const float* __restrict__ mW1,
                                          const float* __restrict__ mW2,
                                          float* __restrict__ msum) {
  const int bx    = blockIdx.x;              // B * 4 * JSPLIT
  const int jsp   = bx & (JSPLIT - 1);
  const int itile = (bx / JSPLIT) & 3;       // 128-i tile
  const int b     = bx / (JSPLIT * 4);
  const int tid   = threadIdx.x;
  const int w     = tid >> 6;                // wave 0..3 -> i sub-slice of 32
  const int l     = tid & 63;
  const int ln    = l & 15;
  const int q     = l >> 4;

  __shared__ char Plds[4][32 * 256];         // per-wave [32 i'][128 khid] bf16, XOR-swizzled

  // ---- A1 frags: A[m=khid][k=t] = W1e^T, zero-padded t>=10. 8 m-tiles.
  short8 A1[8];
#pragma unroll
  for (int mt = 0; mt < 8; ++mt) {
    float v[8];
#pragma unroll
    for (int e = 0; e < 8; ++e) {
      int t = q * 8 + e;
      v[e] = (t < Tn) ? mW1[(t * 5 + 4) * MH + mt * 16 + ln] : 0.f;
    }
    A1[mt] = pack8(v);
  }
  // ---- B2 frags: B[k=khid][n=c] = W2. 4 k-tiles x 2 c-tiles.
  short8 B2[4][2];
#pragma unroll
  for (int kt = 0; kt < 4; ++kt)
#pragma unroll
    for (int ct = 0; ct < 2; ++ct) {
      float v[8];
#pragma unroll
      for (int e = 0; e < 8; ++e)
        v[e] = mW2[(kt * 32 + q * 8 + e) * MD + ct * 16 + ln];
      B2[kt][ct] = pack8(v);
    }

  floatx4 acc[2][2];
#pragma unroll
  for (int a = 0; a < 2; ++a)
#pragma unroll
    for (int c = 0; c < 2; ++c) acc[a][c] = (floatx4)0.f;

  char* lbase = &Plds[w][0];
  const int ibase = itile * 128 + w * 32;    // global i of this wave's slice

#pragma unroll 1
  for (int jj = 0; jj < JPB; ++jj) {
    const int j = jsp * JPB + jj;

    // ---- E frags: B[k=t][n=i'] from x[b,j,t,4+i], zero-padded t>=10
    const float* xp = x + (size_t)(b * Nn + j) * Tn * Fn + 4 + ibase;
    short8 B1[2];
#pragma unroll
    for (int nt = 0; nt < 2; ++nt) {
      float v[8];
#pragma unroll
      for (int e = 0; e < 8; ++e) {
        int t = q * 8 + e;
        v[e] = (t < Tn) ? xp[(size_t)t * Fn + nt * 16 + ln] : 0.f;
      }
      B1[nt] = pack8(v);
    }

    // ---- GEMM1: D1[m=khid][n=i'] = W1e^T.E^T + Abase ; relu -> bf16 -> LDS [i'][khid]
    const float* Ab = Abase + (size_t)(b * Nn + j) * MH;
#pragma unroll
    for (int mt = 0; mt < 8; ++mt) {
      floatx4 ci = *(const floatx4*)(Ab + mt * 16 + q * 4);  // khid = mt*16+4q+r
#pragma unroll
      for (int nt = 0; nt < 2; ++nt) {
        floatx4 d = __builtin_amdgcn_mfma_f32_16x16x32_bf16(A1[mt], B1[nt], ci, 0, 0, 0);
        int ip = nt * 16 + ln;               // wave-local i' 0..31
        unsigned lo = pk2(fmaxf(d[0], 0.f), fmaxf(d[1], 0.f));
        unsigned hi = pk2(fmaxf(d[2], 0.f), fmaxf(d[3], 0.f));
        int byte = ip * 256 + ((mt * 32 + q * 8) ^ ((ip & 7) << 4));
        *(uint2*)(lbase + byte) = make_uint2(lo, hi);
      }
    }

    // ---- GEMM2: acc[i' tile][c tile] += P . W2   (A2 read back via swizzled ds_read_b128)
#pragma unroll
    for (int it2 = 0; it2 < 2; ++it2) {
      int ip = it2 * 16 + ln;
#pragma unroll
      for (int kt = 0; kt < 4; ++kt) {
        int byte = ip * 256 + ((kt * 64 + q * 16) ^ ((ip & 7) << 4));
        short8 a2 = *(const short8*)(lbase + byte);
        acc[it2][0] = __builtin_amdgcn_mfma_f32_16x16x32_bf16(a2, B2[kt][0], acc[it2][0], 0, 0, 0);
        acc[it2][1] = __builtin_amdgcn_mfma_f32_16x16x32_bf16(a2, B2[kt][1], acc[it2][1], 0, 0, 0);
      }
    }
  }

  // ---- accumulate into msum
#pragma unroll
  for (int it2 = 0; it2 < 2; ++it2)
#pragma unroll
    for (int ct = 0; ct < 2; ++ct)
#pragma unroll
      for (int r = 0; r < 4; ++r) {
        int i = ibase + it2 * 16 + q * 4 + r;
        int c = ct * 16 + ln;
        atomicAdd(&msum[(size_t)(b * Nn + i) * MD + c], acc[it2][ct][r]);
      }
}

// ---------------- Kernel C: per (b,i) final MLP 36 -> 128 -> 4
__global__ __launch_bounds__(128) void kC(const float* __restrict__ x,
                                          const float* __restrict__ msum,
                                          const float* __restrict__ mb2,
                                          const float* __restrict__ iW1,
                                          const float* __restrict__ ib1,
                                          const float* __restrict__ iW2,
                                          const float* __restrict__ ib2,
                                          float* __restrict__ out) {
  int bi = blockIdx.x;
  int k  = threadIdx.x;
  __shared__ float red[UH][OD];

  const float* ms = msum + (size_t)bi * MD;
  const float* nf = x + ((size_t)bi * Tn + (Tn - 1)) * Fn;

  float a = ib1[k];
#pragma unroll
  for (int c = 0; c < MD; ++c)
    a = fmaf(ms[c] + (float)Nn * mb2[c], iW1[c * UH + k], a);
#pragma unroll
  for (int c = 0; c < 4; ++c)
    a = fmaf(nf[c], iW1[(MD + c) * UH + k], a);
  a = fmaxf(a, 0.f);
#pragma unroll
  for (int c = 0; c < OD; ++c) red[k][c] = a * iW2[k * OD + c];
  __syncthreads();

  if (k < OD) {
    float s = ib2[k];
    for (int kk = 0; kk < UH; ++kk) s += red[kk][k];
    out[(size_t)bi * OD + k] = s;
  }
}

extern "C" void kernel_launch(void* const* d_in, const int* in_sizes, int n_in,
                              void* d_out, int out_size, void* d_ws, size_t ws_size,
                              hipStream_t stream) {
  const float* x   = (const float*)d_in[0];
  const float* mW1 = (const float*)d_in[1];
  const float* mb1 = (const float*)d_in[2];
  const float* mW2 = (const float*)d_in[3];
  const float* mb2 = (const float*)d_in[4];
  const float* iW1 = (const float*)d_in[5];
  const float* ib1 = (const float*)d_in[6];
  const float* iW2 = (const float*)d_in[7];
  const float* ib2 = (const float*)d_in[8];
  float* out = (float*)d_out;

  float* Abase = (float*)d_ws;                         // B*N*128 floats
  float* msum  = Abase + (size_t)Bn * Nn * MH;         // B*N*32 floats

  hipMemsetAsync(msum, 0, (size_t)Bn * Nn * MD * sizeof(float), stream);

  kA<<<Bn * Nn, 128, 0, stream>>>(x, mW1, mb1, Abase);
  kB<<<Bn * 4 * JSPLIT, 256, 0, stream>>>(x, Abase, mW1, mW2, msum);
  kC<<<Bn * Nn, 128, 0, stream>>>(x, msum, mb2, iW1, ib1, iW2, ib2, out);
}

// Round 3
// 88.393 us; speedup vs baseline: 3.7576x; 1.4342x over previous
//
#include <hip/hip_runtime.h>
#include <hip/hip_bf16.h>

#define Bn 4
#define Nn 512
#define Tn 10
#define Fn 516      // N + 4
#define MH 128      // MSG_HID
#define MD 32       // MSG_DIM
#define UH 128      // UPD_HID
#define OD 4        // OUT_DIM

#define JSPLIT 64
#define JPB (Nn / JSPLIT)   // 8 j's per block

typedef __attribute__((ext_vector_type(4))) short short4v;  // 4 bf16 = 2 VGPRs
typedef __attribute__((ext_vector_type(8))) short short8v;
typedef __attribute__((ext_vector_type(4))) float floatx4;

static __device__ inline unsigned pk2(float a, float b) {
  union { __hip_bfloat162 h; unsigned u; } cv;
  cv.h = __float22bfloat162_rn(make_float2(a, b));
  return cv.u;
}
static __device__ inline short4v pack4(float a, float b, float c, float d) {
  union { short4v s; unsigned u[2]; } cv;
  cv.u[0] = pk2(a, b);
  cv.u[1] = pk2(c, d);
  return cv.s;
}

// K=16 bf16 MFMA. A/B frag: lane(ln,q) elem e -> k = 4q+e. D: row m = 4q+r, col n = ln.
#if __has_builtin(__builtin_amdgcn_mfma_f32_16x16x16bf16_1k)
static __device__ inline floatx4 MFMA16(short4v a, short4v b, floatx4 c) {
  return __builtin_amdgcn_mfma_f32_16x16x16bf16_1k(a, b, c, 0, 0, 0);
}
#else
// Fallback: pack K=16 data into elems 0-3 of the K=32 op; A/B pair element-wise
// by k, so zero elems 4-7 contribute 0 and the K=16 result is exact.
static __device__ inline floatx4 MFMA16(short4v a, short4v b, floatx4 c) {
  short8v a8 = {a[0], a[1], a[2], a[3], 0, 0, 0, 0};
  short8v b8 = {b[0], b[1], b[2], b[3], 0, 0, 0, 0};
  return __builtin_amdgcn_mfma_f32_16x16x32_bf16(a8, b8, c, 0, 0, 0);
}
#endif

// ---------------- Kernel A: Abase[b*N+j][128] = mb1 + sum_{t,c<4} x[b,j,t,c]*mW1[5t+c][:]
__global__ __launch_bounds__(128) void kA(const float* __restrict__ x,
                                          const float* __restrict__ mW1,
                                          const float* __restrict__ mb1,
                                          float* __restrict__ Abase) {
  int bj = blockIdx.x;
  int k  = threadIdx.x;
  const float* xr = x + (size_t)bj * Tn * Fn;
  float acc = mb1[k];
#pragma unroll
  for (int t = 0; t < Tn; ++t)
#pragma unroll
    for (int c = 0; c < 4; ++c)
      acc = fmaf(xr[t * Fn + c], mW1[(t * 5 + c) * MH + k], acc);
  Abase[(size_t)bj * MH + k] = acc;
}

// ---------------- Kernel B: register-chained MFMA pair-MLP, no LDS.
// GEMM1: P[khid][i'] = W1e^T(128x16) . E^T(16xi') + Abase   (K = t, padded 10->16)
// GEMM2: msum[i'][c] += relu(P)^T . W2                      (K = khid, 8 x 16)
__global__ __launch_bounds__(256, 3) void kB(const float* __restrict__ x,
                                             const float* __restrict__ Abase,
                                             const float* __restrict__ mW1,
                                             const float* __restrict__ mW2,
                                             float* __restrict__ msum) {
  const int bx    = blockIdx.x;              // B * 4 * JSPLIT
  const int jsp   = bx & (JSPLIT - 1);
  const int itile = (bx / JSPLIT) & 3;
  const int b     = bx / (JSPLIT * 4);
  const int tid   = threadIdx.x;
  const int w     = tid >> 6;                // wave -> 32-wide i slice
  const int l     = tid & 63;
  const int ln    = l & 15;
  const int q     = l >> 4;
  const int ibase = itile * 128 + w * 32;

  // ---- A1 frags: A[m=khid][k=t] = W1e^T, zero for t>=10
  short4v A1[8];
#pragma unroll
  for (int mt = 0; mt < 8; ++mt) {
    float v[4];
#pragma unroll
    for (int e = 0; e < 4; ++e) {
      int t = q * 4 + e;
      v[e] = (t < Tn) ? mW1[(t * 5 + 4) * MH + mt * 16 + ln] : 0.f;
    }
    A1[mt] = pack4(v[0], v[1], v[2], v[3]);
  }
  // ---- B2 frags: B[k=khid][n=c] = W2 (8 k-tiles x 2 c-tiles)
  short4v B2[8][2];
#pragma unroll
  for (int kt = 0; kt < 8; ++kt)
#pragma unroll
    for (int ct = 0; ct < 2; ++ct) {
      float v[4];
#pragma unroll
      for (int e = 0; e < 4; ++e)
        v[e] = mW2[(kt * 16 + q * 4 + e) * MD + ct * 16 + ln];
      B2[kt][ct] = pack4(v[0], v[1], v[2], v[3]);
    }

  floatx4 acc[2][2];
#pragma unroll
  for (int a = 0; a < 2; ++a)
#pragma unroll
    for (int c = 0; c < 2; ++c) acc[a][c] = (floatx4)0.f;

#pragma unroll 2
  for (int jj = 0; jj < JPB; ++jj) {
    const int j = jsp * JPB + jj;

    // E frags: B[k=t][n=i'], zero t>=10 (masked loads; coalesced over ln)
    const float* xp = x + (size_t)(b * Nn + j) * Tn * Fn + 4 + ibase;
    short4v B1[2];
#pragma unroll
    for (int nt = 0; nt < 2; ++nt) {
      float v[4];
#pragma unroll
      for (int e = 0; e < 4; ++e) {
        int t = q * 4 + e;
        v[e] = (t < Tn) ? xp[(size_t)t * Fn + nt * 16 + ln] : 0.f;
      }
      B1[nt] = pack4(v[0], v[1], v[2], v[3]);
    }

    // C-input: Abase[khid], khid = mt*16 + 4q + r (L2-resident)
    const float* Ab = Abase + (size_t)(b * Nn + j) * MH;
    floatx4 ci[8];
#pragma unroll
    for (int mt = 0; mt < 8; ++mt)
      ci[mt] = *(const floatx4*)(Ab + mt * 16 + q * 4);

    // Chained GEMM1 -> relu/pack -> GEMM2, all in registers:
    // D1 row (4q+r) == A2 k (4q+e), so the packed D1 tile IS the GEMM2 A-frag.
#pragma unroll
    for (int mt = 0; mt < 8; ++mt) {
      floatx4 d0 = MFMA16(A1[mt], B1[0], ci[mt]);
      floatx4 d1 = MFMA16(A1[mt], B1[1], ci[mt]);
      short4v pa0 = pack4(fmaxf(d0[0], 0.f), fmaxf(d0[1], 0.f),
                          fmaxf(d0[2], 0.f), fmaxf(d0[3], 0.f));
      short4v pa1 = pack4(fmaxf(d1[0], 0.f), fmaxf(d1[1], 0.f),
                          fmaxf(d1[2], 0.f), fmaxf(d1[3], 0.f));
      acc[0][0] = MFMA16(pa0, B2[mt][0], acc[0][0]);
      acc[0][1] = MFMA16(pa0, B2[mt][1], acc[0][1]);
      acc[1][0] = MFMA16(pa1, B2[mt][0], acc[1][0]);
      acc[1][1] = MFMA16(pa1, B2[mt][1], acc[1][1]);
    }
  }

  // ---- accumulate into msum: i = ibase + nt*16 + 4q + r, c = ct*16 + ln
#pragma unroll
  for (int nt = 0; nt < 2; ++nt)
#pragma unroll
    for (int ct = 0; ct < 2; ++ct)
#pragma unroll
      for (int r = 0; r < 4; ++r) {
        int i = ibase + nt * 16 + q * 4 + r;
        int c = ct * 16 + ln;
        atomicAdd(&msum[(size_t)(b * Nn + i) * MD + c], acc[nt][ct][r]);
      }
}

// ---------------- Kernel C: per (b,i) final MLP 36 -> 128 -> 4
__global__ __launch_bounds__(128) void kC(const float* __restrict__ x,
                                          const float* __restrict__ msum,
                                          const float* __restrict__ mb2,
                                          const float* __restrict__ iW1,
                                          const float* __restrict__ ib1,
                                          const float* __restrict__ iW2,
                                          const float* __restrict__ ib2,
                                          float* __restrict__ out) {
  int bi = blockIdx.x;
  int k  = threadIdx.x;
  __shared__ float red[UH][OD];

  const float* ms = msum + (size_t)bi * MD;
  const float* nf = x + ((size_t)bi * Tn + (Tn - 1)) * Fn;

  float a = ib1[k];
#pragma unroll
  for (int c = 0; c < MD; ++c)
    a = fmaf(ms[c] + (float)Nn * mb2[c], iW1[c * UH + k], a);
#pragma unroll
  for (int c = 0; c < 4; ++c)
    a = fmaf(nf[c], iW1[(MD + c) * UH + k], a);
  a = fmaxf(a, 0.f);
#pragma unroll
  for (int c = 0; c < OD; ++c) red[k][c] = a * iW2[k * OD + c];
  __syncthreads();

  if (k < OD) {
    float s = ib2[k];
    for (int kk = 0; kk < UH; ++kk) s += red[kk][k];
    out[(size_t)bi * OD + k] = s;
  }
}

extern "C" void kernel_launch(void* const* d_in, const int* in_sizes, int n_in,
                              void* d_out, int out_size, void* d_ws, size_t ws_size,
                              hipStream_t stream) {
  const float* x   = (const float*)d_in[0];
  const float* mW1 = (const float*)d_in[1];
  const float* mb1 = (const float*)d_in[2];
  const float* mW2 = (const float*)d_in[3];
  const float* mb2 = (const float*)d_in[4];
  const float* iW1 = (const float*)d_in[5];
  const float* ib1 = (const float*)d_in[6];
  const float* iW2 = (const float*)d_in[7];
  const float* ib2 = (const float*)d_in[8];
  float* out = (float*)d_out;

  float* Abase = (float*)d_ws;                         // B*N*128 floats
  float* msum  = Abase + (size_t)Bn * Nn * MH;         // B*N*32 floats

  hipMemsetAsync(msum, 0, (size_t)Bn * Nn * MD * sizeof(float), stream);

  kA<<<Bn * Nn, 128, 0, stream>>>(x, mW1, mb1, Abase);
  kB<<<Bn * 4 * JSPLIT, 256, 0, stream>>>(x, Abase, mW1, mW2, msum);
  kC<<<Bn * Nn, 128, 0, stream>>>(x, msum, mb2, iW1, ib1, iW2, ib2, out);
}

// Round 4
// 64.394 us; speedup vs baseline: 5.1581x; 1.3727x over previous
//
#include <hip/hip_runtime.h>
#include <hip/hip_bf16.h>

#define Bn 4
#define Nn 512
#define Tn 10
#define Fn 516      // N + 4
#define MH 128      // MSG_HID
#define MD 32       // MSG_DIM
#define UH 128      // UPD_HID
#define OD 4        // OUT_DIM

#define JSPLIT 64
#define JPB (Nn / JSPLIT)   // 8 j's per block

typedef __attribute__((ext_vector_type(4))) short short4v;  // 4 bf16 = 2 VGPRs
typedef __attribute__((ext_vector_type(8))) short short8v;
typedef __attribute__((ext_vector_type(4))) float floatx4;

static __device__ inline unsigned pk2(float a, float b) {
  union { __hip_bfloat162 h; unsigned u; } cv;
  cv.h = __float22bfloat162_rn(make_float2(a, b));
  return cv.u;
}
static __device__ inline short4v pack4(float a, float b, float c, float d) {
  union { short4v s; unsigned u[2]; } cv;
  cv.u[0] = pk2(a, b);
  cv.u[1] = pk2(c, d);
  return cv.s;
}

// K=16 bf16 MFMA. A/B frag: lane(ln,q) elem e -> k = 4q+e. D: row m = 4q+r, col n = ln.
#if __has_builtin(__builtin_amdgcn_mfma_f32_16x16x16bf16_1k)
static __device__ inline floatx4 MFMA16(short4v a, short4v b, floatx4 c) {
  return __builtin_amdgcn_mfma_f32_16x16x16bf16_1k(a, b, c, 0, 0, 0);
}
#else
// Fallback: K=16 data in elems 0-3 of the K=32 op pairs k-wise; zero tail is exact.
static __device__ inline floatx4 MFMA16(short4v a, short4v b, floatx4 c) {
  short8v a8 = {a[0], a[1], a[2], a[3], 0, 0, 0, 0};
  short8v b8 = {b[0], b[1], b[2], b[3], 0, 0, 0, 0};
  return __builtin_amdgcn_mfma_f32_16x16x32_bf16(a8, b8, c, 0, 0, 0);
}
#endif

// ---------------- Kernel A: Abase[b*N+j][128] = mb1 + sum_{t,c<4} x[b,j,t,c]*mW1[5t+c][:]
__global__ __launch_bounds__(128) void kA(const float* __restrict__ x,
                                          const float* __restrict__ mW1,
                                          const float* __restrict__ mb1,
                                          float* __restrict__ Abase) {
  int bj = blockIdx.x;
  int k  = threadIdx.x;
  const float* xr = x + (size_t)bj * Tn * Fn;
  float acc = mb1[k];
#pragma unroll
  for (int t = 0; t < Tn; ++t)
#pragma unroll
    for (int c = 0; c < 4; ++c)
      acc = fmaf(xr[t * Fn + c], mW1[(t * 5 + c) * MH + k], acc);
  Abase[(size_t)bj * MH + k] = acc;
}

// ---------------- Kernel B: register-chained MFMA pair-MLP.
// GEMM1: P[khid][i'] = W1e^T(128x16) . E^T(16xi') + Abase   (K = t, padded 10->16)
// GEMM2: msum[i'][c] += relu(P)^T . W2                      (K = khid, 8 x 16)
// Abase staged in LDS per block; E loads software-pipelined via unroll-4.
__global__ __launch_bounds__(256, 4) void kB(const float* __restrict__ x,
                                             const float* __restrict__ Abase,
                                             const float* __restrict__ mW1,
                                             const float* __restrict__ mW2,
                                             float* __restrict__ msum) {
  const int bx    = blockIdx.x;              // B * 4 * JSPLIT
  const int jsp   = bx & (JSPLIT - 1);
  const int itile = (bx / JSPLIT) & 3;
  const int b     = bx / (JSPLIT * 4);
  const int tid   = threadIdx.x;
  const int w     = tid >> 6;                // wave -> 32-wide i slice
  const int l     = tid & 63;
  const int ln    = l & 15;
  const int q     = l >> 4;
  const int ibase = itile * 128 + w * 32;

  __shared__ float ciL[JPB][MH];             // 4 KB: Abase rows for this block's 8 j's

  // ---- cooperative stage: 8 rows x 128 floats, contiguous in Abase
  {
    const float4* src = (const float4*)(Abase + (size_t)(b * Nn + jsp * JPB) * MH);
    float4* dst = (float4*)&ciL[0][0];
#pragma unroll
    for (int u = 0; u < 2; ++u)
      dst[tid + u * 256] = src[tid + u * 256];
  }

  // ---- A1 frags: A[m=khid][k=t] = W1e^T, zero for t>=10
  short4v A1[8];
#pragma unroll
  for (int mt = 0; mt < 8; ++mt) {
    float v[4];
#pragma unroll
    for (int e = 0; e < 4; ++e) {
      int t = q * 4 + e;
      v[e] = (t < Tn) ? mW1[(t * 5 + 4) * MH + mt * 16 + ln] : 0.f;
    }
    A1[mt] = pack4(v[0], v[1], v[2], v[3]);
  }
  // ---- B2 frags: B[k=khid][n=c] = W2 (8 k-tiles x 2 c-tiles)
  short4v B2[8][2];
#pragma unroll
  for (int kt = 0; kt < 8; ++kt)
#pragma unroll
    for (int ct = 0; ct < 2; ++ct) {
      float v[4];
#pragma unroll
      for (int e = 0; e < 4; ++e)
        v[e] = mW2[(kt * 16 + q * 4 + e) * MD + ct * 16 + ln];
      B2[kt][ct] = pack4(v[0], v[1], v[2], v[3]);
    }

  floatx4 acc[2][2];
#pragma unroll
  for (int a = 0; a < 2; ++a)
#pragma unroll
    for (int c = 0; c < 2; ++c) acc[a][c] = (floatx4)0.f;

  __syncthreads();

#pragma unroll 4
  for (int jj = 0; jj < JPB; ++jj) {
    const int j = jsp * JPB + jj;

    // E frags: B[k=t][n=i'], zero t>=10 (coalesced over ln)
    const float* xp = x + (size_t)(b * Nn + j) * Tn * Fn + 4 + ibase;
    short4v B1[2];
#pragma unroll
    for (int nt = 0; nt < 2; ++nt) {
      float v[4];
#pragma unroll
      for (int e = 0; e < 4; ++e) {
        int t = q * 4 + e;
        v[e] = (t < Tn) ? xp[(size_t)t * Fn + nt * 16 + ln] : 0.f;
      }
      B1[nt] = pack4(v[0], v[1], v[2], v[3]);
    }

    // Chained GEMM1 -> relu/pack -> GEMM2, C-input from LDS.
    // D1 row (4q+r) == A2 k (4q+e): the packed D1 tile IS the GEMM2 A-frag.
#pragma unroll
    for (int mt = 0; mt < 8; ++mt) {
      floatx4 ci = *(const floatx4*)&ciL[jj][mt * 16 + q * 4];
      floatx4 d0 = MFMA16(A1[mt], B1[0], ci);
      floatx4 d1 = MFMA16(A1[mt], B1[1], ci);
      short4v pa0 = pack4(fmaxf(d0[0], 0.f), fmaxf(d0[1], 0.f),
                          fmaxf(d0[2], 0.f), fmaxf(d0[3], 0.f));
      short4v pa1 = pack4(fmaxf(d1[0], 0.f), fmaxf(d1[1], 0.f),
                          fmaxf(d1[2], 0.f), fmaxf(d1[3], 0.f));
      acc[0][0] = MFMA16(pa0, B2[mt][0], acc[0][0]);
      acc[0][1] = MFMA16(pa0, B2[mt][1], acc[0][1]);
      acc[1][0] = MFMA16(pa1, B2[mt][0], acc[1][0]);
      acc[1][1] = MFMA16(pa1, B2[mt][1], acc[1][1]);
    }
  }

  // ---- accumulate into msum: i = ibase + nt*16 + 4q + r, c = ct*16 + ln
#pragma unroll
  for (int nt = 0; nt < 2; ++nt)
#pragma unroll
    for (int ct = 0; ct < 2; ++ct)
#pragma unroll
      for (int r = 0; r < 4; ++r) {
        int i = ibase + nt * 16 + q * 4 + r;
        int c = ct * 16 + ln;
        atomicAdd(&msum[(size_t)(b * Nn + i) * MD + c], acc[nt][ct][r]);
      }
}

// ---------------- Kernel C: per (b,i) final MLP 36 -> 128 -> 4
__global__ __launch_bounds__(128) void kC(const float* __restrict__ x,
                                          const float* __restrict__ msum,
                                          const float* __restrict__ mb2,
                                          const float* __restrict__ iW1,
                                          const float* __restrict__ ib1,
                                          const float* __restrict__ iW2,
                                          const float* __restrict__ ib2,
                                          float* __restrict__ out) {
  int bi = blockIdx.x;
  int k  = threadIdx.x;
  __shared__ float red[UH][OD];

  const float* ms = msum + (size_t)bi * MD;
  const float* nf = x + ((size_t)bi * Tn + (Tn - 1)) * Fn;

  float a = ib1[k];
#pragma unroll
  for (int c = 0; c < MD; ++c)
    a = fmaf(ms[c] + (float)Nn * mb2[c], iW1[c * UH + k], a);
#pragma unroll
  for (int c = 0; c < 4; ++c)
    a = fmaf(nf[c], iW1[(MD + c) * UH + k], a);
  a = fmaxf(a, 0.f);
#pragma unroll
  for (int c = 0; c < OD; ++c) red[k][c] = a * iW2[k * OD + c];
  __syncthreads();

  if (k < OD) {
    float s = ib2[k];
    for (int kk = 0; kk < UH; ++kk) s += red[kk][k];
    out[(size_t)bi * OD + k] = s;
  }
}

extern "C" void kernel_launch(void* const* d_in, const int* in_sizes, int n_in,
                              void* d_out, int out_size, void* d_ws, size_t ws_size,
                              hipStream_t stream) {
  const float* x   = (const float*)d_in[0];
  const float* mW1 = (const float*)d_in[1];
  const float* mb1 = (const float*)d_in[2];
  const float* mW2 = (const float*)d_in[3];
  const float* mb2 = (const float*)d_in[4];
  const float* iW1 = (const float*)d_in[5];
  const float* ib1 = (const float*)d_in[6];
  const float* iW2 = (const float*)d_in[7];
  const float* ib2 = (const float*)d_in[8];
  float* out = (float*)d_out;

  float* Abase = (float*)d_ws;                         // B*N*128 floats
  float* msum  = Abase + (size_t)Bn * Nn * MH;         // B*N*32 floats

  hipMemsetAsync(msum, 0, (size_t)Bn * Nn * MD * sizeof(float), stream);

  kA<<<Bn * Nn, 128, 0, stream>>>(x, mW1, mb1, Abase);
  kB<<<Bn * 4 * JSPLIT, 256, 0, stream>>>(x, Abase, mW1, mW2, msum);
  kC<<<Bn * Nn, 128, 0, stream>>>(x, msum, mb2, iW1, ib1, iW2, ib2, out);
}